// Round 2
// 539.035 us; speedup vs baseline: 1.0179x; 1.0179x over previous
//
#include <hip/hip_runtime.h>
#include <math.h>

#define EMB 128
#define MID 192
#define SEQ 128
#define BATCH 16
#define NPAIR 127
#define KCLS 5
#define EPSF 1e-5f

// ws float-offsets
// WYT: slice s = o*4 + q (q = k-chunk of 64, o = output col) holds
//      WYT[s*64+j] = Wy[q*64+j][o].   (k_seq thread t uses slice t: q=t&3, o=t>>2)
// WXXT: slice s = c*2 + hh holds WXXT[s*64+j] = Wxx[hh*64+j][c].
#define OFF_WYT   0                      // 512*64 = 32768
#define OFF_BY    32768                  // 128
#define OFF_WXXT  32896                  // 512*64 = 32768
#define OFF_BXX   65664                  // 256
#define OFF_NODES 65920                  // B*128*128 = 262144
#define OFF_YC    328064                 // B*127*128 = 260096
#define OFF_L0    588160                 // B*127

// ---------------- composite weights (transposed for per-thread slices) ------
__global__ void k_comp(const float* __restrict__ W1, const float* __restrict__ b1,
                       const float* __restrict__ W2, const float* __restrict__ b2,
                       const float* __restrict__ W3, const float* __restrict__ b3,
                       const float* __restrict__ W4, const float* __restrict__ b4,
                       float* __restrict__ ws) {
    int tid = blockIdx.x * blockDim.x + threadIdx.x;
    if (tid < 32768) {                    // Wy[k][o], k<256, o<128
        int k = tid >> 7, o = tid & 127;
        float a = 0.f;
        for (int j = 0; j < MID; ++j) a += W1[k*MID+j] * W2[j*EMB+o];
        int q = k >> 6, jj = k & 63;
        ws[OFF_WYT + (size_t)(o*4 + q)*64 + jj] = a;
    } else if (tid < 65536) {             // Wxx[k][c], k<128, c<256
        int t = tid - 32768;
        int k = t >> 8, c = t & 255;
        float a = 0.f;
        for (int j = 0; j < MID; ++j) a += W3[k*MID+j] * W4[j*256+c];
        int hh = k >> 6, jj = k & 63;
        ws[OFF_WXXT + (size_t)(c*2 + hh)*64 + jj] = a;
    } else if (tid < 65536 + 128) {       // by
        int o = tid - 65536;
        float a = b2[o];
        for (int j = 0; j < MID; ++j) a += b1[j] * W2[j*EMB+o];
        ws[OFF_BY + o] = a;
    } else if (tid < 65536 + 128 + 256) { // bxx
        int o = tid - 65536 - 128;
        float a = b4[o];
        for (int j = 0; j < MID; ++j) a += b3[j] * W4[j*256+o];
        ws[OFF_BXX + o] = a;
    }
}

// ---------------- gather embeddings ----------------
__global__ void k_nodes(const int* __restrict__ inp, const float* __restrict__ emb,
                        float* __restrict__ ws) {
    int tid = blockIdx.x * blockDim.x + threadIdx.x;  // B*128*128
    if (tid >= BATCH*SEQ*EMB) return;
    int d = tid & 127;
    int bs = tid >> 7;
    int tok = inp[bs];
    ws[OFF_NODES + tid] = emb[tok*EMB + d];
}

// ---------------- initial 127 pair losses: 8 groups x 16 rows ---------------
// launch_bounds(512,1): 128 blocks over 256 CUs -> 1 block/CU anyway; lets
// wy[64]/wxx[64] live in VGPRs instead of scratch.
__global__ void __launch_bounds__(512, 1) k_init(float* __restrict__ ws) {
    __shared__ float s_x[2][2*EMB];
    __shared__ float s_red[4][2][EMB];
    __shared__ float s_redx[2][2][256];
    __shared__ float s_y[2][EMB];
    __shared__ float s_by[EMB];
    __shared__ float s_bxx[2*EMB];
    __shared__ float s_ls[2][2];
    int tid = threadIdx.x;
    int b = blockIdx.x >> 3, g = blockIdx.x & 7;
    float wy[64], wxx[64];
    {
        // WYT layout: slice (o*4 + q); k_init roles: q = tid>>7, o = tid&127
        const float4* gw = (const float4*)(ws + OFF_WYT) + ((size_t)(tid & 127)*4 + (tid >> 7))*16;
        #pragma unroll
        for (int i = 0; i < 16; ++i) { float4 v = gw[i]; wy[4*i]=v.x; wy[4*i+1]=v.y; wy[4*i+2]=v.z; wy[4*i+3]=v.w; }
        // WXXT layout: slice (c*2 + hh); roles: hh = tid>>8, c = tid&255
        const float4* gx = (const float4*)(ws + OFF_WXXT) + ((size_t)(tid & 255)*2 + (tid >> 8))*16;
        #pragma unroll
        for (int i = 0; i < 16; ++i) { float4 v = gx[i]; wxx[4*i]=v.x; wxx[4*i+1]=v.y; wxx[4*i+2]=v.z; wxx[4*i+3]=v.w; }
    }
    if (tid < EMB) s_by[tid] = ws[OFF_BY + tid];
    if (tid < 2*EMB) s_bxx[tid] = ws[OFF_BXX + tid];
    const float* nodes = ws + OFF_NODES + (size_t)b*SEQ*EMB;
    float* yc = ws + OFF_YC + (size_t)b*NPAIR*EMB;
    int q4 = tid >> 7, o = tid & 127;
    int hh = tid >> 8, c = tid & 255;
    int p_s = tid >> 8, kk = tid & 255;
    __syncthreads();
    for (int i = 0; i < 8; ++i) {
        int base = g*16 + i*2;
        {
            int j = base + p_s;
            int jj = j < NPAIR ? j : NPAIR - 1;
            s_x[p_s][kk] = nodes[(jj + (kk < 128 ? 1 : 0))*EMB + (kk & 127)];
        }
        __syncthreads();
        float a0 = 0.f, a1 = 0.f;
        #pragma unroll
        for (int j = 0; j < 64; ++j) {
            float w = wy[j];
            a0 += s_x[0][q4*64 + j] * w;
            a1 += s_x[1][q4*64 + j] * w;
        }
        s_red[q4][0][o] = a0;
        s_red[q4][1][o] = a1;
        __syncthreads();
        if (tid < 256) {
            int p = tid >> 7, oo = tid & 127;
            float yv = s_red[0][p][oo] + s_red[1][p][oo] + s_red[2][p][oo] + s_red[3][p][oo] + s_by[oo];
            s_y[p][oo] = yv;
            int j2 = base + p;
            if (j2 < NPAIR) yc[(size_t)j2*EMB + oo] = yv;
        }
        __syncthreads();
        float c0 = 0.f, c1 = 0.f;
        #pragma unroll
        for (int j = 0; j < 64; ++j) {
            float w = wxx[j];
            c0 += s_y[0][hh*64 + j] * w;
            c1 += s_y[1][hh*64 + j] * w;
        }
        s_redx[hh][0][c] = c0;
        s_redx[hh][1][c] = c1;
        __syncthreads();
        if (tid < 256) {   // waves 0-3: (pair p2, half h2)
            int w = tid >> 6, lane = tid & 63;
            int p2 = w >> 1, h2 = w & 1;
            int cA = h2*128 + lane, cB = cA + 64;
            float v0 = s_redx[0][p2][cA] + s_redx[1][p2][cA] + s_bxx[cA];
            float v1 = s_redx[0][p2][cB] + s_redx[1][p2][cB] + s_bxx[cB];
            float m = fmaxf(v0, v1);
            for (int s = 32; s; s >>= 1) m = fmaxf(m, __shfl_xor(m, s, 64));
            float se = expf(v0 - m) + expf(v1 - m);
            for (int s = 32; s; s >>= 1) se += __shfl_xor(se, s, 64);
            float lse = m + logf(se);
            float o0 = s_x[p2][cA], o1 = s_x[p2][cB];
            float term = o0*(v0 - lse) + o1*(v1 - lse);
            for (int s = 32; s; s >>= 1) term += __shfl_xor(term, s, 64);
            if (lane == 0) s_ls[p2][h2] = -term;
        }
        __syncthreads();
        if (tid < 2) {
            int j2 = base + tid;
            if (j2 < NPAIR) {
                float l = ((1.f+EPSF)*s_ls[tid][0] + (1.f+EPSF)*s_ls[tid][1]) / (2.f + EPSF);
                ws[OFF_L0 + b*NPAIR + j2] = l;
            }
        }
        __syncthreads();
    }
}

// padded staged-x access: chunk stride 72 floats breaks 4-way bank aliasing
#define SX(p, c) s_x[p][(((c) >> 6)*72) + ((c) & 63)]

// ---------------- sequential scan: one block (512 thr) per batch row --------
// 5 barriers/step: stage | y(shfl-reduce) | xx(shfl-reduce) | softmax||rest-argmin | combine+shift
// launch_bounds(512,1): LDS (142.5 KB) already limits to 1 block/CU; the old
// (512,2) bound capped VGPRs at 128 and spilled wy/wxx to scratch.
__global__ void __launch_bounds__(512, 1) k_seq(float* __restrict__ ws,
                      const float* __restrict__ Wk, const float* __restrict__ bkv,
                      float* __restrict__ out) {
    __shared__ float s_nodes[SEQ*EMB];    // 64 KB
    __shared__ float s_yc[NPAIR*EMB];     // 63.5 KB
    __shared__ float s_x[2][4*72];        // padded chunks
    __shared__ float s_y[2][EMB];
    __shared__ float s_xx[2][2*EMB];
    __shared__ float s_by[EMB];
    __shared__ float s_bxx[2*EMB];
    __shared__ float s_ls[2][2];
    __shared__ float s_loss[2][SEQ];      // ping-pong
    __shared__ float s_cnt[2][SEQ];
    __shared__ int   s_nslot[2][SEQ];
    __shared__ int   s_yslot[2][SEQ];
    __shared__ float s_restv[2];
    __shared__ int   s_resti[2];
    __shared__ float s_log[KCLS];

    int tid = threadIdx.x;
    int b = blockIdx.x;
    float wy[64], wxx[64];
    {
        const float4* gw = (const float4*)(ws + OFF_WYT) + (size_t)tid*16;   // slice == tid
        #pragma unroll
        for (int i = 0; i < 16; ++i) { float4 v = gw[i]; wy[4*i]=v.x; wy[4*i+1]=v.y; wy[4*i+2]=v.z; wy[4*i+3]=v.w; }
        const float4* gx = (const float4*)(ws + OFF_WXXT) + (size_t)tid*16;  // slice == tid
        #pragma unroll
        for (int i = 0; i < 16; ++i) { float4 v = gx[i]; wxx[4*i]=v.x; wxx[4*i+1]=v.y; wxx[4*i+2]=v.z; wxx[4*i+3]=v.w; }
    }
    {
        const float4* gn = (const float4*)(ws + OFF_NODES + (size_t)b*SEQ*EMB);
        float4* sn = (float4*)s_nodes;
        for (int i = tid; i < SEQ*EMB/4; i += 512) sn[i] = gn[i];
        const float4* gy = (const float4*)(ws + OFF_YC + (size_t)b*NPAIR*EMB);
        float4* sy = (float4*)s_yc;
        for (int i = tid; i < NPAIR*EMB/4; i += 512) sy[i] = gy[i];
    }
    if (tid < EMB) s_by[tid] = ws[OFF_BY + tid];
    if (tid < 2*EMB) s_bxx[tid] = ws[OFF_BXX + tid];
    if (tid < NPAIR) { s_loss[0][tid] = ws[OFF_L0 + b*NPAIR + tid]; s_yslot[0][tid] = tid; }
    if (tid < SEQ)   { s_cnt[0][tid] = 1.f; s_nslot[0][tid] = tid; }

    float acc = 0.f;
    int cur = 0;
    int q0c = -1, q1c = -1;               // current-step recompute positions (uniform regs)
    int slotFr = 0, ysIr = 0, myslot = 0;
    bool stageYc = false;
    const int q4 = tid & 3,  oy = tid >> 2;   // y roles: k-chunk in lane&3
    const int hh = tid & 1,  cx = tid >> 1;   // xx roles: k-chunk in lane&1
    const int sp = tid >> 8, skk = tid & 255; // stage roles
    __syncthreads();

    #pragma unroll 1
    for (int t = 0; t < NPAIR; ++t) {
        const int L = SEQ - t;
        if (t > 0) {
            // ---- S0: materialize previous father + stage x for the 2 pairs
            if (tid < EMB) s_nodes[slotFr*EMB + tid] = s_yc[(size_t)ysIr*EMB + tid];
            {
                float xv = stageYc ? s_yc[(size_t)ysIr*EMB + (skk & 127)]
                                   : s_nodes[myslot*EMB + (skk & 127)];
                s_x[sp][((skk >> 6)*72) + (skk & 63)] = xv;
            }
            __syncthreads();
            // ---- S1: y = x @ Wy + by (both pairs); shfl-reduce 4 k-chunks
            {
                float a0 = 0.f, a1 = 0.f;
                const float* x0 = &s_x[0][q4*72];
                const float* x1 = &s_x[1][q4*72];
                #pragma unroll
                for (int j = 0; j < 64; ++j) { float w = wy[j]; a0 += x0[j]*w; a1 += x1[j]*w; }
                a0 += __shfl_xor(a0, 1, 64); a1 += __shfl_xor(a1, 1, 64);
                a0 += __shfl_xor(a0, 2, 64); a1 += __shfl_xor(a1, 2, 64);
                if (q4 == 0) {
                    float bb = s_by[oy];
                    float y0 = a0 + bb, y1 = a1 + bb;
                    s_y[0][oy] = y0; s_y[1][oy] = y1;
                    s_yc[(size_t)s_yslot[cur][q0c]*EMB + oy] = y0;
                    s_yc[(size_t)s_yslot[cur][q1c]*EMB + oy] = y1;
                }
            }
            __syncthreads();
            // ---- S2: xx = y @ Wxx + bxx; shfl-reduce 2 k-chunks
            {
                float c0 = 0.f, c1 = 0.f;
                const float* y0p = &s_y[0][hh*64];
                const float* y1p = &s_y[1][hh*64];
                #pragma unroll
                for (int j = 0; j < 64; ++j) { float w = wxx[j]; c0 += y0p[j]*w; c1 += y1p[j]*w; }
                c0 += __shfl_xor(c0, 1, 64); c1 += __shfl_xor(c1, 1, 64);
                if (hh == 0) {
                    float bb = s_bxx[cx];
                    s_xx[0][cx] = c0 + bb;
                    s_xx[1][cx] = c1 + bb;
                }
            }
            __syncthreads();
        }
        // ---- S3: softmax losses (waves 0-1, 32-lane groups, fused reductions)
        //          || argmin over unchanged losses (waves 2-3)
        if (t > 0 && tid < 128) {
            int p2 = tid >> 6, h2 = (tid >> 5) & 1, l5 = tid & 31;
            int base = h2*128 + l5;
            float v0 = s_xx[p2][base],      v1 = s_xx[p2][base+32];
            float v2 = s_xx[p2][base+64],   v3 = s_xx[p2][base+96];
            float o0 = SX(p2, base),        o1 = SX(p2, base+32);
            float o2 = SX(p2, base+64),     o3 = SX(p2, base+96);
            float m   = fmaxf(fmaxf(v0, v1), fmaxf(v2, v3));
            float sov = v0*o0 + v1*o1 + v2*o2 + v3*o3;
            float so  = (o0 + o1) + (o2 + o3);
            for (int s = 16; s; s >>= 1) {
                m    = fmaxf(m, __shfl_xor(m, s, 64));
                sov += __shfl_xor(sov, s, 64);
                so  += __shfl_xor(so, s, 64);
            }
            float se = expf(v0 - m) + expf(v1 - m) + expf(v2 - m) + expf(v3 - m);
            for (int s = 16; s; s >>= 1) se += __shfl_xor(se, s, 64);
            if (l5 == 0) s_ls[p2][h2] = (m + logf(se))*so - sov;   // = -sum o*(v-lse)
        } else if (tid >= 128 && tid < 256) {
            int j = tid - 128;
            float v = (j <= L-2 && j != q0c && j != q1c) ? s_loss[cur][j] : INFINITY;
            int ii = j;
            for (int s = 32; s; s >>= 1) {
                float ov = __shfl_xor(v, s, 64);
                int   oi = __shfl_xor(ii, s, 64);
                if (ov < v || (ov == v && oi < ii)) { v = ov; ii = oi; }
            }
            if ((tid & 63) == 0) { s_restv[(tid >> 6) - 2] = v; s_resti[(tid >> 6) - 2] = ii; }
        }
        __syncthreads();
        // ---- S4: uniform combine (redundant, all threads) + ping-pong shift
        float l0 = INFINITY, l1 = INFINITY;
        if (t > 0) {
            float n1a = s_cnt[cur][q0c+1], n2a = s_cnt[cur][q0c];
            l0 = ((n1a + EPSF)*s_ls[0][0] + (n2a + EPSF)*s_ls[0][1]) / (n1a + n2a + EPSF);
            float n1b = s_cnt[cur][q1c+1], n2b = s_cnt[cur][q1c];
            l1 = ((n1b + EPSF)*s_ls[1][0] + (n2b + EPSF)*s_ls[1][1]) / (n1b + n2b + EPSF);
        }
        float bv = s_restv[0]; int bi = s_resti[0];
        {
            float rv = s_restv[1]; int ri = s_resti[1];
            if (rv < bv || (rv == bv && ri < bi)) { bv = rv; bi = ri; }
        }
        if (t > 0) {   // q1 first then q0, so q0 wins ties (first-index rule)
            if (l1 < bv || (l1 == bv && q1c < bi)) { bv = l1; bi = q1c; }
            if (l0 < bv || (l0 == bv && q0c < bi)) { bv = l0; bi = q0c; }
        }
        if (tid == 0) acc += bv;
        const int idx = bi;
        const int pos = idx > 0 ? idx - 1 : 0;
        const bool dS = idx > 0;
        const float fcnt = s_cnt[cur][idx] + s_cnt[cur][idx == 0 ? L-1 : idx-1];
        slotFr = s_nslot[cur][pos];
        ysIr   = s_yslot[cur][idx];
        const int nxt = cur ^ 1;
        if (tid < NPAIR) {
            int sh = (dS && tid >= pos+1 && tid <= L-3) ? 1 : 0;
            int sj = tid + sh;
            float v = (sj == q0c) ? l0 : (sj == q1c) ? l1 : s_loss[cur][sj];
            s_loss[nxt][tid]  = v;
            s_yslot[nxt][tid] = s_yslot[cur][sj];
        }
        if (tid < SEQ) {
            int sh = (dS && tid >= pos+1 && tid <= L-2) ? 1 : 0;
            s_cnt[nxt][tid]   = (tid == pos) ? fcnt : s_cnt[cur][tid + sh];
            s_nslot[nxt][tid] = s_nslot[cur][tid + sh];
        }
        // next-step roles + per-thread stage slot prefetch (off next critical path)
        q0c = pos >= 1 ? pos - 1 : 0;
        q1c = pos;
        {
            int qq = (sp ? q1c : q0c) + (skk < 128 ? 1 : 0);
            stageYc = (qq == q1c);   // father position reads fresh y from yc
            int sh = (dS && qq >= pos+1 && qq <= L-2) ? 1 : 0;
            myslot = s_nslot[cur][qq + sh];
        }
        cur = nxt;
        __syncthreads();
    }
    // ---- prediction from root = yc[ysIr] (the last father)
    {
        int w = tid >> 6, l = tid & 63;
        if (w < KCLS) {
            const float* root = s_yc + (size_t)ysIr*EMB;
            float p = root[2*l]*Wk[(2*l)*KCLS + w] + root[2*l+1]*Wk[(2*l+1)*KCLS + w];
            for (int s = 32; s; s >>= 1) p += __shfl_xor(p, s, 64);
            if (l == 0) s_log[w] = p + bkv[w];
        }
    }
    __syncthreads();
    if (tid == 0) {
        int best = 0;
        for (int cc = 1; cc < KCLS; ++cc) if (s_log[cc] > s_log[best]) best = cc;
        out[b] = (float)best;
        atomicAdd(&out[BATCH], acc * (1.f/16.f));
    }
}

extern "C" void kernel_launch(void* const* d_in, const int* in_sizes, int n_in,
                              void* d_out, int out_size, void* d_ws, size_t ws_size,
                              hipStream_t stream) {
    const int*   inp = (const int*)d_in[0];
    const float* emb = (const float*)d_in[1];
    const float* W1  = (const float*)d_in[2];
    const float* b1  = (const float*)d_in[3];
    const float* W2  = (const float*)d_in[4];
    const float* b2  = (const float*)d_in[5];
    const float* W3  = (const float*)d_in[6];
    const float* b3  = (const float*)d_in[7];
    const float* W4  = (const float*)d_in[8];
    const float* b4  = (const float*)d_in[9];
    const float* Wk  = (const float*)d_in[10];
    const float* bk  = (const float*)d_in[11];
    float* out = (float*)d_out;
    float* ws  = (float*)d_ws;

    hipMemsetAsync(d_out, 0, (size_t)out_size * sizeof(float), stream);

    k_comp<<<(65920 + 255) / 256, 256, 0, stream>>>(W1, b1, W2, b2, W3, b3, W4, b4, ws);
    k_nodes<<<(BATCH*SEQ*EMB + 255) / 256, 256, 0, stream>>>(inp, emb, ws);
    k_init<<<BATCH * 8, 512, 0, stream>>>(ws);
    k_seq<<<BATCH, 512, 0, stream>>>(ws, Wk, bk, out);
}